// Round 3
// baseline (292.203 us; speedup 1.0000x reference)
//
#include <hip/hip_runtime.h>
#include <math.h>

// ============================================================================
// DIAGNOSTIC ROUND (v4): pass1 and gather each run their full workload TWICE
// internally (numerically idempotent). Purpose: dur_us_R3 - dur_us_R2 = p + g
// (their true combined duration), and if 2p or 2g > ~92us the kernel surfaces
// in the rocprof top-5 with its own counters (fills otherwise clog the list).
// pass1 halves its accumulator (exact); gather re-writes identical outputs
// with a memory clobber between reps to block restrict-based dead-store DCE.
// ============================================================================

#define VOCAB 50257
#define DIM 768
#define RANK 16
#define SCALING 2.0f   // ALPHA / RANK = 32/16

constexpr int P1_BLOCKS = 1024;
constexpr int P1_THREADS = 192;                                     // 3 waves; each thread owns 4 columns
constexpr int ROWS_PER_BLOCK = (VOCAB + P1_BLOCKS - 1) / P1_BLOCKS; // 50
constexpr int RED_THREADS = 256;
constexpr int RED_COLS = 16;                 // columns per reduce block
constexpr int RED_BLOCKS = DIM / RED_COLS;   // 48
constexpr int TOKENS_PER_BLOCK = 8;
constexpr int G_THREADS = 192;

// ---------------- Pass 1: per-block partial column sum-of-squares ----------------
__global__ __launch_bounds__(P1_THREADS, 4) void dora_pass1(
    const float* __restrict__ emb, const float* __restrict__ lora_a,
    const float* __restrict__ lora_b, float* __restrict__ partials) {
  const int t = threadIdx.x;     // 0..191
  const int c4 = t * 4;          // base column of this thread's float4 group

  float4 B[RANK];
#pragma unroll
  for (int k = 0; k < RANK; ++k)
    B[k] = *reinterpret_cast<const float4*>(lora_b + k * DIM + c4);

  const int r0 = blockIdx.x * ROWS_PER_BLOCK;
  const int rcnt = min(ROWS_PER_BLOCK, VOCAB - r0);

  const float* __restrict__ ebase = emb + (size_t)r0 * DIM + c4;
  const float* __restrict__ abase = lora_a + (size_t)r0 * RANK;

  float4 acc = make_float4(0.f, 0.f, 0.f, 0.f);

  for (int rep = 0; rep < 2; ++rep) {   // DIAGNOSTIC x2 (acc halved at end)
    int i = 0;
    for (; i + 4 <= rcnt; i += 4) {
      float4 e[4];
#pragma unroll
      for (int r = 0; r < 4; ++r)
        e[r] = *reinterpret_cast<const float4*>(ebase + (size_t)(i + r) * DIM);

      float4 d[4];
#pragma unroll
      for (int r = 0; r < 4; ++r) d[r] = make_float4(0.f, 0.f, 0.f, 0.f);

#pragma unroll
      for (int k = 0; k < RANK; ++k) {
#pragma unroll
        for (int r = 0; r < 4; ++r) {
          const float a = abase[(size_t)(i + r) * RANK + k];
          d[r].x = fmaf(a, B[k].x, d[r].x);
          d[r].y = fmaf(a, B[k].y, d[r].y);
          d[r].z = fmaf(a, B[k].z, d[r].z);
          d[r].w = fmaf(a, B[k].w, d[r].w);
        }
      }
#pragma unroll
      for (int r = 0; r < 4; ++r) {
        const float cx = fmaf(SCALING, d[r].x, e[r].x);
        const float cy = fmaf(SCALING, d[r].y, e[r].y);
        const float cz = fmaf(SCALING, d[r].z, e[r].z);
        const float cw = fmaf(SCALING, d[r].w, e[r].w);
        acc.x = fmaf(cx, cx, acc.x);
        acc.y = fmaf(cy, cy, acc.y);
        acc.z = fmaf(cz, cz, acc.z);
        acc.w = fmaf(cw, cw, acc.w);
      }
    }
    for (; i < rcnt; ++i) {
      const float4 ev = *reinterpret_cast<const float4*>(ebase + (size_t)i * DIM);
      float dx = 0.f, dy = 0.f, dz = 0.f, dw = 0.f;
#pragma unroll
      for (int k = 0; k < RANK; ++k) {
        const float a = abase[(size_t)i * RANK + k];
        dx = fmaf(a, B[k].x, dx);
        dy = fmaf(a, B[k].y, dy);
        dz = fmaf(a, B[k].z, dz);
        dw = fmaf(a, B[k].w, dw);
      }
      const float cx = fmaf(SCALING, dx, ev.x);
      const float cy = fmaf(SCALING, dy, ev.y);
      const float cz = fmaf(SCALING, dz, ev.z);
      const float cw = fmaf(SCALING, dw, ev.w);
      acc.x = fmaf(cx, cx, acc.x);
      acc.y = fmaf(cy, cy, acc.y);
      acc.z = fmaf(cz, cz, acc.z);
      acc.w = fmaf(cw, cw, acc.w);
    }
    asm volatile("" ::: "memory");      // keep reps ordered / un-fused
  }
  acc.x *= 0.5f; acc.y *= 0.5f; acc.z *= 0.5f; acc.w *= 0.5f;   // undo the x2
  *reinterpret_cast<float4*>(partials + (size_t)blockIdx.x * DIM + c4) = acc;
}

// ---------------- Reduce: coalesced column reduction (unchanged, single) ---------
__global__ __launch_bounds__(RED_THREADS) void dora_reduce(
    const float* __restrict__ partials, const float* __restrict__ magnitude,
    float* __restrict__ scale) {
  const int t = threadIdx.x;                 // 0..255
  const int col = t & (RED_COLS - 1);        // 0..15
  const int rgrp = t >> 4;                   // 0..15
  const int c = blockIdx.x * RED_COLS + col;

  float s = 0.f;
#pragma unroll 8
  for (int r = rgrp; r < P1_BLOCKS; r += RED_THREADS / RED_COLS)
    s += partials[(size_t)r * DIM + c];

  s += __shfl_xor(s, 16);
  s += __shfl_xor(s, 32);

  __shared__ float lds[RED_THREADS / 64][RED_COLS];
  const int wave = t >> 6;
  if ((t & 63) < RED_COLS) lds[wave][t & 63] = s;
  __syncthreads();
  if (t < RED_COLS) {
    float tot = lds[0][t] + lds[1][t] + lds[2][t] + lds[3][t];
    const float norm = fmaxf(sqrtf(tot), 1e-8f);
    const int cc = blockIdx.x * RED_COLS + t;
    scale[cc] = magnitude[cc] / norm;
  }
}

// ---------------- Gather: 8 tokens per block (DIAGNOSTIC x2) ----------------
__global__ __launch_bounds__(G_THREADS, 4) void dora_gather(
    const int* __restrict__ tokens, const float* __restrict__ emb,
    const float* __restrict__ lora_a, const float* __restrict__ lora_b,
    const float* __restrict__ scale, float* __restrict__ out, int n_tokens) {
  const int t = threadIdx.x;
  const int c4 = t * 4;

  float4 B[RANK];
#pragma unroll
  for (int k = 0; k < RANK; ++k)
    B[k] = *reinterpret_cast<const float4*>(lora_b + k * DIM + c4);
  const float4 sc = *reinterpret_cast<const float4*>(scale + c4);

  const int tok0 = blockIdx.x * TOKENS_PER_BLOCK;

  for (int rep = 0; rep < 2; ++rep) {   // DIAGNOSTIC x2: identical re-writes
    if (tok0 + TOKENS_PER_BLOCK <= n_tokens) {
      int ids[TOKENS_PER_BLOCK];
#pragma unroll
      for (int i = 0; i < TOKENS_PER_BLOCK; ++i) ids[i] = tokens[tok0 + i];

      float4 e[TOKENS_PER_BLOCK];
#pragma unroll
      for (int i = 0; i < TOKENS_PER_BLOCK; ++i)
        e[i] = *reinterpret_cast<const float4*>(emb + (size_t)ids[i] * DIM + c4);

#pragma unroll
      for (int i = 0; i < TOKENS_PER_BLOCK; ++i) {
        const float* __restrict__ arow = lora_a + (size_t)ids[i] * RANK;
        float dx = 0.f, dy = 0.f, dz = 0.f, dw = 0.f;
#pragma unroll
        for (int k = 0; k < RANK; ++k) {
          const float a = arow[k];
          dx = fmaf(a, B[k].x, dx);
          dy = fmaf(a, B[k].y, dy);
          dz = fmaf(a, B[k].z, dz);
          dw = fmaf(a, B[k].w, dw);
        }
        float4 o;
        o.x = fmaf(SCALING, dx, e[i].x) * sc.x;
        o.y = fmaf(SCALING, dy, e[i].y) * sc.y;
        o.z = fmaf(SCALING, dz, e[i].z) * sc.z;
        o.w = fmaf(SCALING, dw, e[i].w) * sc.w;
        *reinterpret_cast<float4*>(out + (size_t)(tok0 + i) * DIM + c4) = o;
      }
    } else {
      for (int i = 0; i < TOKENS_PER_BLOCK; ++i) {
        const int tok = tok0 + i;
        if (tok >= n_tokens) break;
        const int id = tokens[tok];
        const float* __restrict__ arow = lora_a + (size_t)id * RANK;
        const float4 ev = *reinterpret_cast<const float4*>(emb + (size_t)id * DIM + c4);
        float dx = 0.f, dy = 0.f, dz = 0.f, dw = 0.f;
#pragma unroll
        for (int k = 0; k < RANK; ++k) {
          const float a = arow[k];
          dx = fmaf(a, B[k].x, dx);
          dy = fmaf(a, B[k].y, dy);
          dz = fmaf(a, B[k].z, dz);
          dw = fmaf(a, B[k].w, dw);
        }
        float4 o;
        o.x = fmaf(SCALING, dx, ev.x) * sc.x;
        o.y = fmaf(SCALING, dy, ev.y) * sc.y;
        o.z = fmaf(SCALING, dz, ev.z) * sc.z;
        o.w = fmaf(SCALING, dw, ev.w) * sc.w;
        *reinterpret_cast<float4*>(out + (size_t)tok * DIM + c4) = o;
      }
    }
    asm volatile("" ::: "memory");   // block dead-store elim of rep 0 (restrict!)
  }
}

extern "C" void kernel_launch(void* const* d_in, const int* in_sizes, int n_in,
                              void* d_out, int out_size, void* d_ws, size_t ws_size,
                              hipStream_t stream) {
  const int*   tokens    = (const int*)d_in[0];    // [8,2048] int32
  const float* emb       = (const float*)d_in[1];  // [V, D]
  const float* lora_a    = (const float*)d_in[2];  // [V, R]
  const float* lora_b    = (const float*)d_in[3];  // [R, D]
  const float* magnitude = (const float*)d_in[4];  // [D]
  float* out = (float*)d_out;

  const int n_tokens = in_sizes[0];                // 16384

  float* partials = (float*)d_ws;                                  // P1_BLOCKS * DIM floats
  float* scale    = (float*)d_ws + (size_t)P1_BLOCKS * DIM;        // DIM floats

  dora_pass1<<<P1_BLOCKS, P1_THREADS, 0, stream>>>(emb, lora_a, lora_b, partials);
  dora_reduce<<<RED_BLOCKS, RED_THREADS, 0, stream>>>(partials, magnitude, scale);

  const int gather_blocks = (n_tokens + TOKENS_PER_BLOCK - 1) / TOKENS_PER_BLOCK;
  dora_gather<<<gather_blocks, G_THREADS, 0, stream>>>(tokens, emb, lora_a, lora_b,
                                                       scale, out, n_tokens);
}

// Round 4
// 264.412 us; speedup vs baseline: 1.1051x; 1.1051x over previous
//
#include <hip/hip_runtime.h>
#include <math.h>

// ============================================================================
// v5: revert v4's diagnostic x2 (which measured true kernel cost ~35us of the
// ~267us window; the rest is harness poison-fills). Structure = v3 (best
// measured, 266.9us) + gather now does 16 tokens/block as two 8-token batches
// sharing one B-preload (halves aggregate lora_b re-reads and grid size).
// ============================================================================

#define VOCAB 50257
#define DIM 768
#define RANK 16
#define SCALING 2.0f   // ALPHA / RANK = 32/16

constexpr int P1_BLOCKS = 1024;
constexpr int P1_THREADS = 192;                                     // 3 waves; each thread owns 4 columns
constexpr int ROWS_PER_BLOCK = (VOCAB + P1_BLOCKS - 1) / P1_BLOCKS; // 50
constexpr int RED_THREADS = 256;
constexpr int RED_COLS = 16;                 // columns per reduce block
constexpr int RED_BLOCKS = DIM / RED_COLS;   // 48
constexpr int TOKENS_PER_BLOCK = 16;         // two 8-token batches per block
constexpr int BATCH = 8;
constexpr int G_THREADS = 192;

// ---------------- Pass 1: per-block partial column sum-of-squares ----------------
// __launch_bounds__(192,4) pins VGPR<=128 -> 4 waves/SIMD. 4-row chunks with all
// four float4 emb loads issued before any FMA -> 4 KB in flight per wave.
__global__ __launch_bounds__(P1_THREADS, 4) void dora_pass1(
    const float* __restrict__ emb, const float* __restrict__ lora_a,
    const float* __restrict__ lora_b, float* __restrict__ partials) {
  const int t = threadIdx.x;     // 0..191
  const int c4 = t * 4;          // base column of this thread's float4 group

  // B[:, c4..c4+3] in registers: 16 x float4 = 64 VGPRs
  float4 B[RANK];
#pragma unroll
  for (int k = 0; k < RANK; ++k)
    B[k] = *reinterpret_cast<const float4*>(lora_b + k * DIM + c4);

  const int r0 = blockIdx.x * ROWS_PER_BLOCK;
  const int rcnt = min(ROWS_PER_BLOCK, VOCAB - r0);

  const float* __restrict__ ebase = emb + (size_t)r0 * DIM + c4;
  const float* __restrict__ abase = lora_a + (size_t)r0 * RANK;   // wave-uniform -> scalar loads

  float4 acc = make_float4(0.f, 0.f, 0.f, 0.f);

  int i = 0;
  for (; i + 4 <= rcnt; i += 4) {
    float4 e[4];
#pragma unroll
    for (int r = 0; r < 4; ++r)
      e[r] = *reinterpret_cast<const float4*>(ebase + (size_t)(i + r) * DIM);

    float4 d[4];
#pragma unroll
    for (int r = 0; r < 4; ++r) d[r] = make_float4(0.f, 0.f, 0.f, 0.f);

#pragma unroll
    for (int k = 0; k < RANK; ++k) {
#pragma unroll
      for (int r = 0; r < 4; ++r) {
        const float a = abase[(size_t)(i + r) * RANK + k];   // SGPR broadcast loads
        d[r].x = fmaf(a, B[k].x, d[r].x);
        d[r].y = fmaf(a, B[k].y, d[r].y);
        d[r].z = fmaf(a, B[k].z, d[r].z);
        d[r].w = fmaf(a, B[k].w, d[r].w);
      }
    }
#pragma unroll
    for (int r = 0; r < 4; ++r) {
      const float cx = fmaf(SCALING, d[r].x, e[r].x);
      const float cy = fmaf(SCALING, d[r].y, e[r].y);
      const float cz = fmaf(SCALING, d[r].z, e[r].z);
      const float cw = fmaf(SCALING, d[r].w, e[r].w);
      acc.x = fmaf(cx, cx, acc.x);
      acc.y = fmaf(cy, cy, acc.y);
      acc.z = fmaf(cz, cz, acc.z);
      acc.w = fmaf(cw, cw, acc.w);
    }
  }
  for (; i < rcnt; ++i) {
    const float4 ev = *reinterpret_cast<const float4*>(ebase + (size_t)i * DIM);
    float dx = 0.f, dy = 0.f, dz = 0.f, dw = 0.f;
#pragma unroll
    for (int k = 0; k < RANK; ++k) {
      const float a = abase[(size_t)i * RANK + k];
      dx = fmaf(a, B[k].x, dx);
      dy = fmaf(a, B[k].y, dy);
      dz = fmaf(a, B[k].z, dz);
      dw = fmaf(a, B[k].w, dw);
    }
    const float cx = fmaf(SCALING, dx, ev.x);
    const float cy = fmaf(SCALING, dy, ev.y);
    const float cz = fmaf(SCALING, dz, ev.z);
    const float cw = fmaf(SCALING, dw, ev.w);
    acc.x = fmaf(cx, cx, acc.x);
    acc.y = fmaf(cy, cy, acc.y);
    acc.z = fmaf(cz, cz, acc.z);
    acc.w = fmaf(cw, cw, acc.w);
  }
  // every block writes its slot (zeros for idle tail blocks) -> no ws zero-init needed
  *reinterpret_cast<float4*>(partials + (size_t)blockIdx.x * DIM + c4) = acc;
}

// ---------------- Reduce: coalesced column reduction ----------------
__global__ __launch_bounds__(RED_THREADS) void dora_reduce(
    const float* __restrict__ partials, const float* __restrict__ magnitude,
    float* __restrict__ scale) {
  const int t = threadIdx.x;                 // 0..255
  const int col = t & (RED_COLS - 1);        // 0..15
  const int rgrp = t >> 4;                   // 0..15
  const int c = blockIdx.x * RED_COLS + col;

  float s = 0.f;
#pragma unroll 8
  for (int r = rgrp; r < P1_BLOCKS; r += RED_THREADS / RED_COLS)  // 64 iters, 8 in flight
    s += partials[(size_t)r * DIM + c];

  // lanes {x, x^16, x^32, x^48} share a column -> butterfly over bits 4,5
  s += __shfl_xor(s, 16);
  s += __shfl_xor(s, 32);

  __shared__ float lds[RED_THREADS / 64][RED_COLS];
  const int wave = t >> 6;
  if ((t & 63) < RED_COLS) lds[wave][t & 63] = s;
  __syncthreads();
  if (t < RED_COLS) {
    float tot = lds[0][t] + lds[1][t] + lds[2][t] + lds[3][t];
    const float norm = fmaxf(sqrtf(tot), 1e-8f);
    const int cc = blockIdx.x * RED_COLS + t;
    scale[cc] = magnitude[cc] / norm;
  }
}

// ---------------- Gather: 16 tokens per block = two 8-token batches ----------------
// Each batch: load 8 ids, issue all 8 emb-row float4 loads (8 KB in flight per
// wave), then compute. B preload shared across both batches.
__global__ __launch_bounds__(G_THREADS, 4) void dora_gather(
    const int* __restrict__ tokens, const float* __restrict__ emb,
    const float* __restrict__ lora_a, const float* __restrict__ lora_b,
    const float* __restrict__ scale, float* __restrict__ out, int n_tokens) {
  const int t = threadIdx.x;
  const int c4 = t * 4;

  float4 B[RANK];
#pragma unroll
  for (int k = 0; k < RANK; ++k)
    B[k] = *reinterpret_cast<const float4*>(lora_b + k * DIM + c4);
  const float4 sc = *reinterpret_cast<const float4*>(scale + c4);

  const int blk0 = blockIdx.x * TOKENS_PER_BLOCK;

  for (int half = 0; half < TOKENS_PER_BLOCK / BATCH; ++half) {
    const int tok0 = blk0 + half * BATCH;

    if (tok0 + BATCH <= n_tokens) {
      // ---- fast path: all 8 tokens valid ----
      int ids[BATCH];
#pragma unroll
      for (int i = 0; i < BATCH; ++i) ids[i] = tokens[tok0 + i];  // wave-uniform

      float4 e[BATCH];
#pragma unroll
      for (int i = 0; i < BATCH; ++i)
        e[i] = *reinterpret_cast<const float4*>(emb + (size_t)ids[i] * DIM + c4);

#pragma unroll
      for (int i = 0; i < BATCH; ++i) {
        const float* __restrict__ arow = lora_a + (size_t)ids[i] * RANK;  // scalar loads
        float dx = 0.f, dy = 0.f, dz = 0.f, dw = 0.f;
#pragma unroll
        for (int k = 0; k < RANK; ++k) {
          const float a = arow[k];
          dx = fmaf(a, B[k].x, dx);
          dy = fmaf(a, B[k].y, dy);
          dz = fmaf(a, B[k].z, dz);
          dw = fmaf(a, B[k].w, dw);
        }
        float4 o;
        o.x = fmaf(SCALING, dx, e[i].x) * sc.x;
        o.y = fmaf(SCALING, dy, e[i].y) * sc.y;
        o.z = fmaf(SCALING, dz, e[i].z) * sc.z;
        o.w = fmaf(SCALING, dw, e[i].w) * sc.w;
        *reinterpret_cast<float4*>(out + (size_t)(tok0 + i) * DIM + c4) = o;
      }
    } else {
      // ---- tail path ----
      for (int i = 0; i < BATCH; ++i) {
        const int tok = tok0 + i;
        if (tok >= n_tokens) break;
        const int id = tokens[tok];
        const float* __restrict__ arow = lora_a + (size_t)id * RANK;
        const float4 ev = *reinterpret_cast<const float4*>(emb + (size_t)id * DIM + c4);
        float dx = 0.f, dy = 0.f, dz = 0.f, dw = 0.f;
#pragma unroll
        for (int k = 0; k < RANK; ++k) {
          const float a = arow[k];
          dx = fmaf(a, B[k].x, dx);
          dy = fmaf(a, B[k].y, dy);
          dz = fmaf(a, B[k].z, dz);
          dw = fmaf(a, B[k].w, dw);
        }
        float4 o;
        o.x = fmaf(SCALING, dx, ev.x) * sc.x;
        o.y = fmaf(SCALING, dy, ev.y) * sc.y;
        o.z = fmaf(SCALING, dz, ev.z) * sc.z;
        o.w = fmaf(SCALING, dw, ev.w) * sc.w;
        *reinterpret_cast<float4*>(out + (size_t)tok * DIM + c4) = o;
      }
    }
  }
}

extern "C" void kernel_launch(void* const* d_in, const int* in_sizes, int n_in,
                              void* d_out, int out_size, void* d_ws, size_t ws_size,
                              hipStream_t stream) {
  const int*   tokens    = (const int*)d_in[0];    // [8,2048] int32
  const float* emb       = (const float*)d_in[1];  // [V, D]
  const float* lora_a    = (const float*)d_in[2];  // [V, R]
  const float* lora_b    = (const float*)d_in[3];  // [R, D]
  const float* magnitude = (const float*)d_in[4];  // [D]
  float* out = (float*)d_out;

  const int n_tokens = in_sizes[0];                // 16384

  float* partials = (float*)d_ws;                                  // P1_BLOCKS * DIM floats
  float* scale    = (float*)d_ws + (size_t)P1_BLOCKS * DIM;        // DIM floats

  dora_pass1<<<P1_BLOCKS, P1_THREADS, 0, stream>>>(emb, lora_a, lora_b, partials);
  dora_reduce<<<RED_BLOCKS, RED_THREADS, 0, stream>>>(partials, magnitude, scale);

  const int gather_blocks = (n_tokens + TOKENS_PER_BLOCK - 1) / TOKENS_PER_BLOCK;
  dora_gather<<<gather_blocks, G_THREADS, 0, stream>>>(tokens, emb, lora_a, lora_b,
                                                       scale, out, n_tokens);
}